// Round 5
// baseline (38.004 us; speedup 1.0000x reference)
//
#include <hip/hip_runtime.h>
#include <math.h>

#ifndef USE_NEW_LARTG
#define USE_NEW_LARTG 1   // LAPACK >= 3.10 slartg convention
#endif

#define BB 256
#define NN 4096

// ============ float32 LAPACK-replica (ssyevd path for 3x3, lower) ============
// All arithmetic float32, FMA contraction off, mirroring netlib op order.
// DO NOT change op order / precision here: eigenvector SIGNS depend on the
// exact discrete path (round 1 failed from f64 vs f32 sweep-count mismatch).

__device__ __forceinline__ float ssign_(float a, float b) {
  return (b >= 0.0f) ? fabsf(a) : -fabsf(a);
}

__device__ __forceinline__ float slapy2f_(float x, float y) {
#pragma clang fp contract(off)
  float xa = fabsf(x), ya = fabsf(y);
  float w = fmaxf(xa, ya), z = fminf(xa, ya);
  if (z == 0.0f) return w;
  float q = z / w;
  return w * __fsqrt_rn(1.0f + q * q);
}

__device__ __forceinline__ void slartgf_(float f, float g, float& cs, float& sn, float& r) {
#pragma clang fp contract(off)
#if USE_NEW_LARTG
  if (g == 0.0f) { cs = 1.0f; sn = 0.0f; r = f; }
  else if (f == 0.0f) { cs = 0.0f; sn = (g >= 0.0f) ? 1.0f : -1.0f; r = fabsf(g); }
  else {
    float d = __fsqrt_rn(f * f + g * g);
    cs = fabsf(f) / d;
    r = ssign_(d, f);
    sn = g / r;
  }
#else
  if (g == 0.0f) { cs = 1.0f; sn = 0.0f; r = f; }
  else if (f == 0.0f) { cs = 0.0f; sn = 1.0f; r = g; }
  else {
    float rr = __fsqrt_rn(f * f + g * g);
    cs = f / rr;
    sn = g / rr;
    r = rr;
    if (fabsf(f) > fabsf(g) && cs < 0.0f) { cs = -cs; sn = -sn; r = -r; }
  }
#endif
}

__device__ void slaev2f_(float a, float b, float c, float& rt1, float& rt2,
                         float& cs1, float& sn1) {
#pragma clang fp contract(off)
  float sm = a + c;
  float df = a - c;
  float adf = fabsf(df);
  float tb = b + b;
  float ab = fabsf(tb);
  float acmx, acmn;
  if (fabsf(a) > fabsf(c)) { acmx = a; acmn = c; } else { acmx = c; acmn = a; }
  float rt;
  if (adf > ab)      { float q = ab / adf; rt = adf * __fsqrt_rn(1.0f + q * q); }
  else if (adf < ab) { float q = adf / ab; rt = ab * __fsqrt_rn(1.0f + q * q); }
  else               { rt = ab * __fsqrt_rn(2.0f); }
  int sgn1;
  if (sm < 0.0f)      { rt1 = 0.5f * (sm - rt); sgn1 = -1; rt2 = (acmx / rt1) * acmn - (b / rt1) * b; }
  else if (sm > 0.0f) { rt1 = 0.5f * (sm + rt); sgn1 = 1;  rt2 = (acmx / rt1) * acmn - (b / rt1) * b; }
  else                { rt1 = 0.5f * rt; rt2 = -0.5f * rt; sgn1 = 1; }
  float cs;
  int sgn2;
  if (df >= 0.0f) { cs = df + rt; sgn2 = 1; } else { cs = df - rt; sgn2 = -1; }
  float acs = fabsf(cs);
  if (acs > ab) {
    float ct = -tb / cs;
    sn1 = 1.0f / __fsqrt_rn(1.0f + ct * ct);
    cs1 = ct * sn1;
  } else {
    if (ab == 0.0f) { cs1 = 1.0f; sn1 = 0.0f; }
    else { float tn = -cs / tb; cs1 = 1.0f / __fsqrt_rn(1.0f + tn * tn); sn1 = tn * cs1; }
  }
  if (sgn1 == sgn2) { float tn = cs1; cs1 = -sn1; sn1 = tn; }
}

// ssteqr('I') specialized for n=3. d[1..3], e[1..2], z[1..3][1..3] (1-based).
__device__ void steqr3f_(float* d, float* e, float z[4][4]) {
#pragma clang fp contract(off)
  const float eps = 5.9604645e-08f;
  const float eps2 = eps * eps;
  const float safmin = 1.17549435e-38f;
  const int n = 3, nm1 = 2, nmaxit = 3 * 30;
  int jtot = 0, l1 = 1;
  int l, m, lsv, lend, lendsv, i, j, ii, k;
  float p, g, r, c, s, f, b, rt1, rt2, tst, anorm, temp, cj, sj;
  float wc[3], ws_[3];
  wc[0] = wc[1] = wc[2] = 0.0f; ws_[0] = ws_[1] = ws_[2] = 0.0f;

L10:
  if (l1 > n) goto L160;
  if (l1 > 1) e[l1 - 1] = 0.0f;
  if (l1 <= nm1) {
    for (m = l1; m <= nm1; ++m) {
      tst = fabsf(e[m]);
      if (tst == 0.0f) goto L30;
      if (tst <= (__fsqrt_rn(fabsf(d[m])) * __fsqrt_rn(fabsf(d[m + 1]))) * eps) {
        e[m] = 0.0f; goto L30;
      }
    }
  }
  m = n;
L30:
  l = l1; lsv = l; lend = m; lendsv = lend; l1 = m + 1;
  if (lend == l) goto L10;
  anorm = 0.0f;
  for (i = l; i <= lend; ++i) anorm = fmaxf(anorm, fabsf(d[i]));
  for (i = l; i <= lend - 1; ++i) anorm = fmaxf(anorm, fabsf(e[i]));
  if (anorm == 0.0f) goto L10;
  if (fabsf(d[lend]) < fabsf(d[l])) { lend = lsv; l = lendsv; }

  if (lend > l) {
L40:
    if (l != lend) {
      for (m = l; m <= lend - 1; ++m) {
        tst = e[m] * e[m];
        if (tst <= (eps2 * fabsf(d[m])) * fabsf(d[m + 1]) + safmin) goto L60;
      }
    }
    m = lend;
L60:
    if (m < lend) e[m] = 0.0f;
    p = d[l];
    if (m == l) goto L80;
    if (m == l + 1) {
      slaev2f_(d[l], e[l], d[l + 1], rt1, rt2, c, s);
      wc[l] = c; ws_[l] = s;
      for (i = 1; i <= 3; ++i) {
        temp = z[i][l + 1];
        z[i][l + 1] = c * temp - s * z[i][l];
        z[i][l]     = s * temp + c * z[i][l];
      }
      d[l] = rt1; d[l + 1] = rt2; e[l] = 0.0f;
      l = l + 2;
      if (l <= lend) goto L40;
      goto L140;
    }
    if (jtot == nmaxit) goto L140;
    jtot = jtot + 1;
    g = (d[l + 1] - p) / (2.0f * e[l]);
    r = slapy2f_(g, 1.0f);
    g = d[m] - p + e[l] / (g + ssign_(r, g));
    s = 1.0f; c = 1.0f; p = 0.0f;
    for (i = m - 1; i >= l; --i) {
      f = s * e[i]; b = c * e[i];
      slartgf_(g, f, c, s, r);
      if (i != m - 1) e[i + 1] = r;
      g = d[i + 1] - p;
      r = (d[i] - g) * s + 2.0f * c * b;
      p = s * r;
      d[i + 1] = g + p;
      g = c * r - b;
      wc[i] = c; ws_[i] = -s;
    }
    for (j = (m - l + 1) - 1; j >= 1; --j) {
      cj = wc[l + j - 1]; sj = ws_[l + j - 1];
      for (i = 1; i <= 3; ++i) {
        temp = z[i][l + j];
        z[i][l + j]     = cj * temp - sj * z[i][l + j - 1];
        z[i][l + j - 1] = sj * temp + cj * z[i][l + j - 1];
      }
    }
    d[l] = d[l] - p;
    e[l] = g;
    goto L40;
L80:
    d[l] = p;
    l = l + 1;
    if (l <= lend) goto L40;
    goto L140;
  } else {
L90:
    if (l != lend) {
      for (m = l; m >= lend + 1; --m) {
        tst = e[m - 1] * e[m - 1];
        if (tst <= (eps2 * fabsf(d[m])) * fabsf(d[m - 1]) + safmin) goto L110;
      }
    }
    m = lend;
L110:
    if (m > lend) e[m - 1] = 0.0f;
    p = d[l];
    if (m == l) goto L130;
    if (m == l - 1) {
      slaev2f_(d[l - 1], e[l - 1], d[l], rt1, rt2, c, s);
      wc[m] = c; ws_[m] = s;
      for (i = 1; i <= 3; ++i) {
        temp = z[i][l];
        z[i][l]     = c * temp - s * z[i][l - 1];
        z[i][l - 1] = s * temp + c * z[i][l - 1];
      }
      d[l - 1] = rt1; d[l] = rt2; e[l - 1] = 0.0f;
      l = l - 2;
      if (l >= lend) goto L90;
      goto L140;
    }
    if (jtot == nmaxit) goto L140;
    jtot = jtot + 1;
    g = (d[l - 1] - p) / (2.0f * e[l - 1]);
    r = slapy2f_(g, 1.0f);
    g = d[m] - p + e[l - 1] / (g + ssign_(r, g));
    s = 1.0f; c = 1.0f; p = 0.0f;
    for (i = m; i <= l - 1; ++i) {
      f = s * e[i]; b = c * e[i];
      slartgf_(g, f, c, s, r);
      if (i != m) e[i - 1] = r;
      g = d[i] - p;
      r = (d[i + 1] - g) * s + 2.0f * c * b;
      p = s * r;
      d[i] = g + p;
      g = c * r - b;
      wc[i] = c; ws_[i] = s;
    }
    for (j = 1; j <= (l - m + 1) - 1; ++j) {
      cj = wc[m + j - 1]; sj = ws_[m + j - 1];
      for (i = 1; i <= 3; ++i) {
        temp = z[i][m + j];
        z[i][m + j]     = cj * temp - sj * z[i][m + j - 1];
        z[i][m + j - 1] = sj * temp + cj * z[i][m + j - 1];
      }
    }
    d[l] = d[l] - p;
    e[l - 1] = g;
    goto L90;
L130:
    d[l] = p;
    l = l - 1;
    if (l >= lend) goto L90;
    goto L140;
  }
L140:
  if (jtot < nmaxit) goto L10;
  goto L190;
L160:
  for (ii = 2; ii <= n; ++ii) {
    i = ii - 1; k = i; p = d[i];
    for (j = ii; j <= n; ++j) {
      if (d[j] < p) { k = j; p = d[j]; }
    }
    if (k != i) {
      d[k] = d[i]; d[i] = p;
      for (int q = 1; q <= 3; ++q) { temp = z[q][i]; z[q][i] = z[q][k]; z[q][k] = temp; }
    }
  }
L190:
  return;
}

// Full ssyevd path for 3x3 symmetric (lower): ssytd2 + steqr3f + Householder apply.
__device__ void eigh3f_(const float C[3][3], float V[3][3]) {
#pragma clang fp contract(off)
  float a11 = C[0][0], a21 = C[1][0], a31 = C[2][0];
  float a22 = C[1][1], a32 = C[2][1], a33 = C[2][2];
  float d[4], e[3], tau1, v3;
  float xnorm = fabsf(a31);
  if (xnorm == 0.0f) {
    tau1 = 0.0f; v3 = 0.0f;
    d[1] = a11; d[2] = a22; d[3] = a33; e[1] = a21; e[2] = a32;
  } else {
    float beta = -ssign_(slapy2f_(a21, xnorm), a21);
    tau1 = (beta - a21) / beta;
    v3 = a31 / (a21 - beta);
    e[1] = beta;
    float x1 = tau1 * a22 + tau1 * (a32 * v3);
    float x2 = tau1 * a32 + (tau1 * v3) * a33;
    float al = -0.5f * tau1 * (x1 + x2 * v3);
    float w1 = x1 + al;
    float w2 = x2 + al * v3;
    d[1] = a11;
    d[2] = (a22 - w1) - w1;
    e[2] = (a32 - v3 * w1) - w2;
    d[3] = (a33 - v3 * w2) - w2 * v3;
  }
  float z[4][4];
  for (int i = 1; i <= 3; ++i)
    for (int j = 1; j <= 3; ++j) z[i][j] = (i == j) ? 1.0f : 0.0f;
  steqr3f_(d, e, z);
  if (tau1 != 0.0f) {
    for (int j = 1; j <= 3; ++j) {
      float wj = z[2][j] + z[3][j] * v3;
      float tmp = -(tau1 * wj);
      z[2][j] = z[2][j] + tmp;
      z[3][j] = z[3][j] + v3 * tmp;
    }
  }
  for (int i = 0; i < 3; ++i)
    for (int j = 0; j < 3; ++j) V[i][j] = z[i + 1][j + 1];
}

// ====================== Kernel 1: partial moments per (batch, chunk) ======================
// 1024 blocks x 256 threads = 4 blocks/CU. Each block: 1024 points.
__global__ __launch_bounds__(256, 4) void k_part(
    const float* __restrict__ X, const float* __restrict__ mask,
    double* __restrict__ wpart) {
  int blk = blockIdx.x;
  int b = blk >> 2;
  int chunk = blk & 3;
  int t = threadIdx.x;

  const float4* Xv = reinterpret_cast<const float4*>(X);
  int fi = b * 3072 + chunk * 768 + 3 * t;
  float4 v0 = Xv[fi], v1 = Xv[fi + 1], v2 = Xv[fi + 2];
  float4 mm = reinterpret_cast<const float4*>(mask)[b * 1024 + chunk * 256 + t];
  float px[4] = {v0.x, v0.w, v1.z, v2.y};
  float py[4] = {v0.y, v1.x, v1.w, v2.z};
  float pz[4] = {v0.z, v1.y, v2.x, v2.w};
  float pm[4] = {mm.x, mm.y, mm.z, mm.w};

  double acc[11];
#pragma unroll
  for (int q = 0; q < 11; ++q) acc[q] = 0.0;
#pragma unroll
  for (int q = 0; q < 4; ++q) {
    double x = px[q], y = py[q], zz = pz[q], m = pm[q];
    acc[0] += m;       acc[1] += m * m;
    acc[2] += m * x;   acc[3] += m * y;   acc[4] += m * zz;
    acc[5] += x * x;   acc[6] += x * y;   acc[7] += x * zz;
    acc[8] += y * y;   acc[9] += y * zz;  acc[10] += zz * zz;
  }
#pragma unroll
  for (int off = 32; off > 0; off >>= 1)
#pragma unroll
    for (int q = 0; q < 11; ++q) acc[q] += __shfl_down(acc[q], off, 64);

  __shared__ double sh[4][11];
  int wid = t >> 6, lane = t & 63;
  if (lane == 0)
    for (int q = 0; q < 11; ++q) sh[wid][q] = acc[q];
  __syncthreads();
  if (t == 0) {
    double* wp = wpart + (size_t)blk * 11;
    for (int q = 0; q < 11; ++q)
      wp[q] = sh[0][q] + sh[1][q] + sh[2][q] + sh[3][q];
  }
}

// ====================== Kernel 2: redundant eigh + apply ======================
// 1024 blocks x 256 threads, same blk mapping as K1 (L2 reuse of X/mask).
// Thread 0: combine 4 partials (fixed order, bit-identical across siblings)
// + f32 LAPACK-replica eigh, hidden behind the block's X/mask loads.
__global__ __launch_bounds__(256, 4) void k_apply2(
    const float* __restrict__ X, const float* __restrict__ mask,
    const double* __restrict__ wpart,
    float* __restrict__ out_fops, float* __restrict__ out_center,
    float* __restrict__ h) {
  int blk = blockIdx.x;
  int b = blk >> 2;
  int chunk = blk & 3;
  int t = threadIdx.x;

  // Issue X/mask loads first (consumed after the eigh barrier).
  const float4* Xv = reinterpret_cast<const float4*>(X);
  int fi = b * 3072 + chunk * 768 + 3 * t;
  float4 v0 = Xv[fi], v1 = Xv[fi + 1], v2 = Xv[fi + 2];
  float4 mm = reinterpret_cast<const float4*>(mask)[b * 1024 + chunk * 256 + t];

  __shared__ float svc[12];
  if (t == 0) {
    const double* base = wpart + (size_t)(b * 4) * 11;
    double r[11];
    for (int q = 0; q < 11; ++q)
      r[q] = base[q] + base[11 + q] + base[22 + q] + base[33 + q];
    double W = r[0], W2 = r[1];
    double ssum[3] = {r[2], r[3], r[4]};
    double M[3][3] = {{r[5], r[6], r[7]}, {r[6], r[8], r[9]}, {r[7], r[9], r[10]}};
    double cc[3] = {ssum[0] / W, ssum[1] / W, ssum[2] / W};
    float Cf[3][3];
    for (int i = 0; i < 3; ++i)
      for (int j = 0; j < 3; ++j)
        Cf[i][j] = (float)(M[i][j] - (ssum[i] * cc[j] + cc[i] * ssum[j]) + W2 * cc[i] * cc[j]);
    float Vf[3][3];
    eigh3f_(Cf, Vf);
    float cf[3] = {(float)cc[0], (float)cc[1], (float)cc[2]};
    for (int i = 0; i < 3; ++i)
      for (int j = 0; j < 3; ++j) svc[i * 3 + j] = Vf[i][j];
    svc[9] = cf[0]; svc[10] = cf[1]; svc[11] = cf[2];
    if (chunk == 0) {
      out_center[b * 3 + 0] = cf[0];
      out_center[b * 3 + 1] = cf[1];
      out_center[b * 3 + 2] = cf[2];
      for (int o = 0; o < 8; ++o) {
        float sgn[3] = {(o & 4) ? 1.f : -1.f, (o & 2) ? 1.f : -1.f, (o & 1) ? 1.f : -1.f};
        for (int i = 0; i < 3; ++i)
          for (int j = 0; j < 3; ++j)
            out_fops[b * 72 + o * 9 + i * 3 + j] = sgn[j] * Vf[i][j];
      }
    }
  }
  __syncthreads();

  float V0 = svc[0], V1 = svc[1], V2 = svc[2];
  float V3 = svc[3], V4 = svc[4], V5 = svc[5];
  float V6 = svc[6], V7 = svc[7], V8 = svc[8];
  float c0 = svc[9], c1 = svc[10], c2 = svc[11];

  float px[4] = {v0.x, v0.w, v1.z, v2.y};
  float py[4] = {v0.y, v1.x, v1.w, v2.z};
  float pz[4] = {v0.z, v1.y, v2.x, v2.w};
  float pm[4] = {mm.x, mm.y, mm.z, mm.w};

  float ya[4], yb[4], yc[4];
#pragma unroll
  for (int q = 0; q < 4; ++q) {
    float xcx = px[q] - c0 * pm[q];
    float xcy = py[q] - c1 * pm[q];
    float xcz = pz[q] - c2 * pm[q];
    ya[q] = V0 * xcx + V3 * xcy + V6 * xcz;
    yb[q] = V1 * xcx + V4 * xcy + V7 * xcz;
    yc[q] = V2 * xcx + V5 * xcy + V8 * xcz;
  }

  // Stage y tile in LDS in exact output float layout, then coalesced stores.
  __shared__ float ylds[3072];  // 12 KB
  float4* yv = reinterpret_cast<float4*>(ylds);
  yv[3 * t]     = make_float4(ya[0], yb[0], yc[0], ya[1]);
  yv[3 * t + 1] = make_float4(yb[1], yc[1], ya[2], yb[2]);
  yv[3 * t + 2] = make_float4(yc[2], ya[3], yb[3], yc[3]);
  __syncthreads();

  uint4 r0 = reinterpret_cast<const uint4*>(ylds)[t];
  uint4 r1 = reinterpret_cast<const uint4*>(ylds)[t + 256];
  uint4 r2 = reinterpret_cast<const uint4*>(ylds)[t + 512];

  int c0i = t % 3;
  int c1i = c0i + 1; if (c1i == 3) c1i = 0;
  int c2i = c1i + 1; if (c2i == 3) c2i = 0;

  uint4* hv = reinterpret_cast<uint4*>(h);
  int hb = 3072 * (b * 8) + 768 * chunk;
#pragma unroll
  for (int o = 0; o < 8; ++o) {
    unsigned s0 = (o & 4) ? 0u : 0x80000000u;
    unsigned s1 = (o & 2) ? 0u : 0x80000000u;
    unsigned s2 = (o & 1) ? 0u : 0x80000000u;
    unsigned sg[3] = {s0, s1, s2};
    uint4 m0 = make_uint4(sg[c0i], sg[c1i], sg[c2i], sg[c0i]);
    uint4 m1 = make_uint4(sg[c1i], sg[c2i], sg[c0i], sg[c1i]);
    uint4 m2 = make_uint4(sg[c2i], sg[c0i], sg[c1i], sg[c2i]);
    int base = hb + 3072 * o;
    hv[base + t]       = make_uint4(r0.x ^ m0.x, r0.y ^ m0.y, r0.z ^ m0.z, r0.w ^ m0.w);
    hv[base + t + 256] = make_uint4(r1.x ^ m1.x, r1.y ^ m1.y, r1.z ^ m1.z, r1.w ^ m1.w);
    hv[base + t + 512] = make_uint4(r2.x ^ m2.x, r2.y ^ m2.y, r2.z ^ m2.z, r2.w ^ m2.w);
  }
}

// ====================== launch ======================
extern "C" void kernel_launch(void* const* d_in, const int* in_sizes, int n_in,
                              void* d_out, int out_size, void* d_ws, size_t ws_size,
                              hipStream_t stream) {
  const float* X = (const float*)d_in[0];
  const float* mask = (const float*)d_in[1];
  float* out = (float*)d_out;
  float* h = out;                                        // [B*8, N, 3]
  float* fops = out + (size_t)BB * 8 * NN * 3;           // [B, 8, 3, 3]
  float* center = fops + (size_t)BB * 8 * 9;             // [B, 3]
  double* wpart = (double*)d_ws;                         // 11 f64 per block (1024 blocks)

  hipLaunchKernelGGL(k_part, dim3(BB * 4), dim3(256), 0, stream, X, mask, wpart);
  hipLaunchKernelGGL(k_apply2, dim3(BB * 4), dim3(256), 0, stream,
                     X, mask, wpart, fops, center, h);
}

// Round 6
// 36.957 us; speedup vs baseline: 1.0283x; 1.0283x over previous
//
#include <hip/hip_runtime.h>
#include <math.h>

#ifndef USE_NEW_LARTG
#define USE_NEW_LARTG 1   // LAPACK >= 3.10 slartg convention
#endif

#define BB 256
#define NN 4096

// ============ float32 LAPACK-replica (ssyevd path for 3x3, lower) ============
// All arithmetic float32, FMA contraction off, mirroring netlib op order.
// DO NOT change op order / precision here: eigenvector SIGNS depend on the
// exact discrete path (round 1 failed from f64 vs f32 sweep-count mismatch).
// Working arrays live in LDS (__shared__): runtime-indexed locals would go to
// scratch (~10x slower serial chain). Memory placement does not alter FP results.

__device__ __forceinline__ float ssign_(float a, float b) {
  return (b >= 0.0f) ? fabsf(a) : -fabsf(a);
}

__device__ __forceinline__ float slapy2f_(float x, float y) {
#pragma clang fp contract(off)
  float xa = fabsf(x), ya = fabsf(y);
  float w = fmaxf(xa, ya), z = fminf(xa, ya);
  if (z == 0.0f) return w;
  float q = z / w;
  return w * __fsqrt_rn(1.0f + q * q);
}

__device__ __forceinline__ void slartgf_(float f, float g, float& cs, float& sn, float& r) {
#pragma clang fp contract(off)
#if USE_NEW_LARTG
  if (g == 0.0f) { cs = 1.0f; sn = 0.0f; r = f; }
  else if (f == 0.0f) { cs = 0.0f; sn = (g >= 0.0f) ? 1.0f : -1.0f; r = fabsf(g); }
  else {
    float d = __fsqrt_rn(f * f + g * g);
    cs = fabsf(f) / d;
    r = ssign_(d, f);
    sn = g / r;
  }
#else
  if (g == 0.0f) { cs = 1.0f; sn = 0.0f; r = f; }
  else if (f == 0.0f) { cs = 0.0f; sn = 1.0f; r = g; }
  else {
    float rr = __fsqrt_rn(f * f + g * g);
    cs = f / rr;
    sn = g / rr;
    r = rr;
    if (fabsf(f) > fabsf(g) && cs < 0.0f) { cs = -cs; sn = -sn; r = -r; }
  }
#endif
}

__device__ void slaev2f_(float a, float b, float c, float& rt1, float& rt2,
                         float& cs1, float& sn1) {
#pragma clang fp contract(off)
  float sm = a + c;
  float df = a - c;
  float adf = fabsf(df);
  float tb = b + b;
  float ab = fabsf(tb);
  float acmx, acmn;
  if (fabsf(a) > fabsf(c)) { acmx = a; acmn = c; } else { acmx = c; acmn = a; }
  float rt;
  if (adf > ab)      { float q = ab / adf; rt = adf * __fsqrt_rn(1.0f + q * q); }
  else if (adf < ab) { float q = adf / ab; rt = ab * __fsqrt_rn(1.0f + q * q); }
  else               { rt = ab * __fsqrt_rn(2.0f); }
  int sgn1;
  if (sm < 0.0f)      { rt1 = 0.5f * (sm - rt); sgn1 = -1; rt2 = (acmx / rt1) * acmn - (b / rt1) * b; }
  else if (sm > 0.0f) { rt1 = 0.5f * (sm + rt); sgn1 = 1;  rt2 = (acmx / rt1) * acmn - (b / rt1) * b; }
  else                { rt1 = 0.5f * rt; rt2 = -0.5f * rt; sgn1 = 1; }
  float cs;
  int sgn2;
  if (df >= 0.0f) { cs = df + rt; sgn2 = 1; } else { cs = df - rt; sgn2 = -1; }
  float acs = fabsf(cs);
  if (acs > ab) {
    float ct = -tb / cs;
    sn1 = 1.0f / __fsqrt_rn(1.0f + ct * ct);
    cs1 = ct * sn1;
  } else {
    if (ab == 0.0f) { cs1 = 1.0f; sn1 = 0.0f; }
    else { float tn = -cs / tb; cs1 = 1.0f / __fsqrt_rn(1.0f + tn * tn); sn1 = tn * cs1; }
  }
  if (sgn1 == sgn2) { float tn = cs1; cs1 = -sn1; sn1 = tn; }
}

// ssteqr('I') specialized for n=3. d[1..3], e[1..2], z[1..3][1..3] (1-based).
// d, e, z point to LDS. wc/ws_ are LDS (runtime-indexed).
__device__ void steqr3f_(float* d, float* e, float (*z)[4]) {
#pragma clang fp contract(off)
  const float eps = 5.9604645e-08f;
  const float eps2 = eps * eps;
  const float safmin = 1.17549435e-38f;
  const int n = 3, nm1 = 2, nmaxit = 3 * 30;
  int jtot = 0, l1 = 1;
  int l, m, lsv, lend, lendsv, i, j, ii, k;
  float p, g, r, c, s, f, b, rt1, rt2, tst, anorm, temp, cj, sj;
  __shared__ float wc[3];
  __shared__ float ws_[3];
  wc[0] = wc[1] = wc[2] = 0.0f; ws_[0] = ws_[1] = ws_[2] = 0.0f;

L10:
  if (l1 > n) goto L160;
  if (l1 > 1) e[l1 - 1] = 0.0f;
  if (l1 <= nm1) {
    for (m = l1; m <= nm1; ++m) {
      tst = fabsf(e[m]);
      if (tst == 0.0f) goto L30;
      if (tst <= (__fsqrt_rn(fabsf(d[m])) * __fsqrt_rn(fabsf(d[m + 1]))) * eps) {
        e[m] = 0.0f; goto L30;
      }
    }
  }
  m = n;
L30:
  l = l1; lsv = l; lend = m; lendsv = lend; l1 = m + 1;
  if (lend == l) goto L10;
  anorm = 0.0f;
  for (i = l; i <= lend; ++i) anorm = fmaxf(anorm, fabsf(d[i]));
  for (i = l; i <= lend - 1; ++i) anorm = fmaxf(anorm, fabsf(e[i]));
  if (anorm == 0.0f) goto L10;
  if (fabsf(d[lend]) < fabsf(d[l])) { lend = lsv; l = lendsv; }

  if (lend > l) {
L40:
    if (l != lend) {
      for (m = l; m <= lend - 1; ++m) {
        tst = e[m] * e[m];
        if (tst <= (eps2 * fabsf(d[m])) * fabsf(d[m + 1]) + safmin) goto L60;
      }
    }
    m = lend;
L60:
    if (m < lend) e[m] = 0.0f;
    p = d[l];
    if (m == l) goto L80;
    if (m == l + 1) {
      slaev2f_(d[l], e[l], d[l + 1], rt1, rt2, c, s);
      wc[l] = c; ws_[l] = s;
      for (i = 1; i <= 3; ++i) {
        temp = z[i][l + 1];
        z[i][l + 1] = c * temp - s * z[i][l];
        z[i][l]     = s * temp + c * z[i][l];
      }
      d[l] = rt1; d[l + 1] = rt2; e[l] = 0.0f;
      l = l + 2;
      if (l <= lend) goto L40;
      goto L140;
    }
    if (jtot == nmaxit) goto L140;
    jtot = jtot + 1;
    g = (d[l + 1] - p) / (2.0f * e[l]);
    r = slapy2f_(g, 1.0f);
    g = d[m] - p + e[l] / (g + ssign_(r, g));
    s = 1.0f; c = 1.0f; p = 0.0f;
    for (i = m - 1; i >= l; --i) {
      f = s * e[i]; b = c * e[i];
      slartgf_(g, f, c, s, r);
      if (i != m - 1) e[i + 1] = r;
      g = d[i + 1] - p;
      r = (d[i] - g) * s + 2.0f * c * b;
      p = s * r;
      d[i + 1] = g + p;
      g = c * r - b;
      wc[i] = c; ws_[i] = -s;
    }
    for (j = (m - l + 1) - 1; j >= 1; --j) {
      cj = wc[l + j - 1]; sj = ws_[l + j - 1];
      for (i = 1; i <= 3; ++i) {
        temp = z[i][l + j];
        z[i][l + j]     = cj * temp - sj * z[i][l + j - 1];
        z[i][l + j - 1] = sj * temp + cj * z[i][l + j - 1];
      }
    }
    d[l] = d[l] - p;
    e[l] = g;
    goto L40;
L80:
    d[l] = p;
    l = l + 1;
    if (l <= lend) goto L40;
    goto L140;
  } else {
L90:
    if (l != lend) {
      for (m = l; m >= lend + 1; --m) {
        tst = e[m - 1] * e[m - 1];
        if (tst <= (eps2 * fabsf(d[m])) * fabsf(d[m - 1]) + safmin) goto L110;
      }
    }
    m = lend;
L110:
    if (m > lend) e[m - 1] = 0.0f;
    p = d[l];
    if (m == l) goto L130;
    if (m == l - 1) {
      slaev2f_(d[l - 1], e[l - 1], d[l], rt1, rt2, c, s);
      wc[m] = c; ws_[m] = s;
      for (i = 1; i <= 3; ++i) {
        temp = z[i][l];
        z[i][l]     = c * temp - s * z[i][l - 1];
        z[i][l - 1] = s * temp + c * z[i][l - 1];
      }
      d[l - 1] = rt1; d[l] = rt2; e[l - 1] = 0.0f;
      l = l - 2;
      if (l >= lend) goto L90;
      goto L140;
    }
    if (jtot == nmaxit) goto L140;
    jtot = jtot + 1;
    g = (d[l - 1] - p) / (2.0f * e[l - 1]);
    r = slapy2f_(g, 1.0f);
    g = d[m] - p + e[l - 1] / (g + ssign_(r, g));
    s = 1.0f; c = 1.0f; p = 0.0f;
    for (i = m; i <= l - 1; ++i) {
      f = s * e[i]; b = c * e[i];
      slartgf_(g, f, c, s, r);
      if (i != m) e[i - 1] = r;
      g = d[i] - p;
      r = (d[i + 1] - g) * s + 2.0f * c * b;
      p = s * r;
      d[i] = g + p;
      g = c * r - b;
      wc[i] = c; ws_[i] = s;
    }
    for (j = 1; j <= (l - m + 1) - 1; ++j) {
      cj = wc[m + j - 1]; sj = ws_[m + j - 1];
      for (i = 1; i <= 3; ++i) {
        temp = z[i][m + j];
        z[i][m + j]     = cj * temp - sj * z[i][m + j - 1];
        z[i][m + j - 1] = sj * temp + cj * z[i][m + j - 1];
      }
    }
    d[l] = d[l] - p;
    e[l - 1] = g;
    goto L90;
L130:
    d[l] = p;
    l = l - 1;
    if (l >= lend) goto L90;
    goto L140;
  }
L140:
  if (jtot < nmaxit) goto L10;
  goto L190;
L160:
  for (ii = 2; ii <= n; ++ii) {
    i = ii - 1; k = i; p = d[i];
    for (j = ii; j <= n; ++j) {
      if (d[j] < p) { k = j; p = d[j]; }
    }
    if (k != i) {
      d[k] = d[i]; d[i] = p;
      for (int q = 1; q <= 3; ++q) { temp = z[q][i]; z[q][i] = z[q][k]; z[q][k] = temp; }
    }
  }
L190:
  return;
}

// Full ssyevd path for 3x3 symmetric (lower): ssytd2 + steqr3f + Householder apply.
// Working arrays in LDS; caller must be single-threaded (t==0 branch).
__device__ void eigh3f_(const float C[3][3], float V[3][3]) {
#pragma clang fp contract(off)
  float a11 = C[0][0], a21 = C[1][0], a31 = C[2][0];
  float a22 = C[1][1], a32 = C[2][1], a33 = C[2][2];
  __shared__ float d[4];
  __shared__ float e[3];
  __shared__ float z[4][4];
  float tau1, v3;
  float xnorm = fabsf(a31);
  if (xnorm == 0.0f) {
    tau1 = 0.0f; v3 = 0.0f;
    d[1] = a11; d[2] = a22; d[3] = a33; e[1] = a21; e[2] = a32;
  } else {
    float beta = -ssign_(slapy2f_(a21, xnorm), a21);
    tau1 = (beta - a21) / beta;
    v3 = a31 / (a21 - beta);
    e[1] = beta;
    float x1 = tau1 * a22 + tau1 * (a32 * v3);
    float x2 = tau1 * a32 + (tau1 * v3) * a33;
    float al = -0.5f * tau1 * (x1 + x2 * v3);
    float w1 = x1 + al;
    float w2 = x2 + al * v3;
    d[1] = a11;
    d[2] = (a22 - w1) - w1;
    e[2] = (a32 - v3 * w1) - w2;
    d[3] = (a33 - v3 * w2) - w2 * v3;
  }
  for (int i = 1; i <= 3; ++i)
    for (int j = 1; j <= 3; ++j) z[i][j] = (i == j) ? 1.0f : 0.0f;
  steqr3f_(d, e, z);
  if (tau1 != 0.0f) {
    for (int j = 1; j <= 3; ++j) {
      float wj = z[2][j] + z[3][j] * v3;
      float tmp = -(tau1 * wj);
      z[2][j] = z[2][j] + tmp;
      z[3][j] = z[3][j] + v3 * tmp;
    }
  }
  for (int i = 0; i < 3; ++i)
    for (int j = 0; j < 3; ++j) V[i][j] = z[i + 1][j + 1];
}

// ====================== Kernel 1: partial moments per (batch, chunk) ======================
// 1024 blocks x 256 threads = 4 blocks/CU. Each block: 1024 points.
__global__ __launch_bounds__(256, 4) void k_part(
    const float* __restrict__ X, const float* __restrict__ mask,
    double* __restrict__ wpart) {
  int blk = blockIdx.x;
  int b = blk >> 2;
  int chunk = blk & 3;
  int t = threadIdx.x;

  const float4* Xv = reinterpret_cast<const float4*>(X);
  int fi = b * 3072 + chunk * 768 + 3 * t;
  float4 v0 = Xv[fi], v1 = Xv[fi + 1], v2 = Xv[fi + 2];
  float4 mm = reinterpret_cast<const float4*>(mask)[b * 1024 + chunk * 256 + t];
  float px[4] = {v0.x, v0.w, v1.z, v2.y};
  float py[4] = {v0.y, v1.x, v1.w, v2.z};
  float pz[4] = {v0.z, v1.y, v2.x, v2.w};
  float pm[4] = {mm.x, mm.y, mm.z, mm.w};

  double acc[11];
#pragma unroll
  for (int q = 0; q < 11; ++q) acc[q] = 0.0;
#pragma unroll
  for (int q = 0; q < 4; ++q) {
    double x = px[q], y = py[q], zz = pz[q], m = pm[q];
    acc[0] += m;       acc[1] += m * m;
    acc[2] += m * x;   acc[3] += m * y;   acc[4] += m * zz;
    acc[5] += x * x;   acc[6] += x * y;   acc[7] += x * zz;
    acc[8] += y * y;   acc[9] += y * zz;  acc[10] += zz * zz;
  }
#pragma unroll
  for (int off = 32; off > 0; off >>= 1)
#pragma unroll
    for (int q = 0; q < 11; ++q) acc[q] += __shfl_down(acc[q], off, 64);

  __shared__ double sh[4][11];
  int wid = t >> 6, lane = t & 63;
  if (lane == 0)
    for (int q = 0; q < 11; ++q) sh[wid][q] = acc[q];
  __syncthreads();
  if (t == 0) {
    double* wp = wpart + (size_t)blk * 11;
    for (int q = 0; q < 11; ++q)
      wp[q] = sh[0][q] + sh[1][q] + sh[2][q] + sh[3][q];
  }
}

// ====================== Kernel 2: redundant eigh + apply ======================
// 1024 blocks x 256 threads, same blk mapping as K1 (L2 reuse of X/mask).
// Thread 0: combine 4 partials (fixed order, bit-identical across siblings)
// + f32 LAPACK-replica eigh (LDS-backed, ~fast), others wait at barrier.
__global__ __launch_bounds__(256, 4) void k_apply2(
    const float* __restrict__ X, const float* __restrict__ mask,
    const double* __restrict__ wpart,
    float* __restrict__ out_fops, float* __restrict__ out_center,
    float* __restrict__ h) {
  int blk = blockIdx.x;
  int b = blk >> 2;
  int chunk = blk & 3;
  int t = threadIdx.x;

  // Issue X/mask loads first (consumed after the eigh barrier).
  const float4* Xv = reinterpret_cast<const float4*>(X);
  int fi = b * 3072 + chunk * 768 + 3 * t;
  float4 v0 = Xv[fi], v1 = Xv[fi + 1], v2 = Xv[fi + 2];
  float4 mm = reinterpret_cast<const float4*>(mask)[b * 1024 + chunk * 256 + t];

  __shared__ float svc[12];
  if (t == 0) {
    const double* base = wpart + (size_t)(b * 4) * 11;
    double r[11];
    for (int q = 0; q < 11; ++q)
      r[q] = base[q] + base[11 + q] + base[22 + q] + base[33 + q];
    double W = r[0], W2 = r[1];
    double ssum[3] = {r[2], r[3], r[4]};
    double M[3][3] = {{r[5], r[6], r[7]}, {r[6], r[8], r[9]}, {r[7], r[9], r[10]}};
    double cc[3] = {ssum[0] / W, ssum[1] / W, ssum[2] / W};
    float Cf[3][3];
    for (int i = 0; i < 3; ++i)
      for (int j = 0; j < 3; ++j)
        Cf[i][j] = (float)(M[i][j] - (ssum[i] * cc[j] + cc[i] * ssum[j]) + W2 * cc[i] * cc[j]);
    float Vf[3][3];
    eigh3f_(Cf, Vf);
    float cf[3] = {(float)cc[0], (float)cc[1], (float)cc[2]};
    for (int i = 0; i < 3; ++i)
      for (int j = 0; j < 3; ++j) svc[i * 3 + j] = Vf[i][j];
    svc[9] = cf[0]; svc[10] = cf[1]; svc[11] = cf[2];
    if (chunk == 0) {
      out_center[b * 3 + 0] = cf[0];
      out_center[b * 3 + 1] = cf[1];
      out_center[b * 3 + 2] = cf[2];
      for (int o = 0; o < 8; ++o) {
        float sgn[3] = {(o & 4) ? 1.f : -1.f, (o & 2) ? 1.f : -1.f, (o & 1) ? 1.f : -1.f};
        for (int i = 0; i < 3; ++i)
          for (int j = 0; j < 3; ++j)
            out_fops[b * 72 + o * 9 + i * 3 + j] = sgn[j] * Vf[i][j];
      }
    }
  }
  __syncthreads();

  float V0 = svc[0], V1 = svc[1], V2 = svc[2];
  float V3 = svc[3], V4 = svc[4], V5 = svc[5];
  float V6 = svc[6], V7 = svc[7], V8 = svc[8];
  float c0 = svc[9], c1 = svc[10], c2 = svc[11];

  float px[4] = {v0.x, v0.w, v1.z, v2.y};
  float py[4] = {v0.y, v1.x, v1.w, v2.z};
  float pz[4] = {v0.z, v1.y, v2.x, v2.w};
  float pm[4] = {mm.x, mm.y, mm.z, mm.w};

  float ya[4], yb[4], yc[4];
#pragma unroll
  for (int q = 0; q < 4; ++q) {
    float xcx = px[q] - c0 * pm[q];
    float xcy = py[q] - c1 * pm[q];
    float xcz = pz[q] - c2 * pm[q];
    ya[q] = V0 * xcx + V3 * xcy + V6 * xcz;
    yb[q] = V1 * xcx + V4 * xcy + V7 * xcz;
    yc[q] = V2 * xcx + V5 * xcy + V8 * xcz;
  }

  // Stage y tile in LDS in exact output float layout, then coalesced stores.
  __shared__ float ylds[3072];  // 12 KB
  float4* yv = reinterpret_cast<float4*>(ylds);
  yv[3 * t]     = make_float4(ya[0], yb[0], yc[0], ya[1]);
  yv[3 * t + 1] = make_float4(yb[1], yc[1], ya[2], yb[2]);
  yv[3 * t + 2] = make_float4(yc[2], ya[3], yb[3], yc[3]);
  __syncthreads();

  uint4 r0 = reinterpret_cast<const uint4*>(ylds)[t];
  uint4 r1 = reinterpret_cast<const uint4*>(ylds)[t + 256];
  uint4 r2 = reinterpret_cast<const uint4*>(ylds)[t + 512];

  // Leading component of each slot: t%3, (t+1)%3, (t+2)%3.
  int c0i = t % 3;
  bool e0 = (c0i == 0), e1 = (c0i == 1);

  uint4* hv = reinterpret_cast<uint4*>(h);
  int hb = 3072 * (b * 8) + 768 * chunk;
#pragma unroll
  for (int o = 0; o < 8; ++o) {
    // compile-time per-component sign words (o unrolled)
    unsigned s0 = (o & 4) ? 0u : 0x80000000u;
    unsigned s1 = (o & 2) ? 0u : 0x80000000u;
    unsigned s2 = (o & 1) ? 0u : 0x80000000u;
    // rotate (s0,s1,s2) by c0i -- register cndmask, no runtime-indexed array
    unsigned ma = e0 ? s0 : (e1 ? s1 : s2);
    unsigned mb = e0 ? s1 : (e1 ? s2 : s0);
    unsigned mc = e0 ? s2 : (e1 ? s0 : s1);
    int base = hb + 3072 * o;
    hv[base + t]       = make_uint4(r0.x ^ ma, r0.y ^ mb, r0.z ^ mc, r0.w ^ ma);
    hv[base + t + 256] = make_uint4(r1.x ^ mb, r1.y ^ mc, r1.z ^ ma, r1.w ^ mb);
    hv[base + t + 512] = make_uint4(r2.x ^ mc, r2.y ^ ma, r2.z ^ mb, r2.w ^ mc);
  }
}

// ====================== launch ======================
extern "C" void kernel_launch(void* const* d_in, const int* in_sizes, int n_in,
                              void* d_out, int out_size, void* d_ws, size_t ws_size,
                              hipStream_t stream) {
  const float* X = (const float*)d_in[0];
  const float* mask = (const float*)d_in[1];
  float* out = (float*)d_out;
  float* h = out;                                        // [B*8, N, 3]
  float* fops = out + (size_t)BB * 8 * NN * 3;           // [B, 8, 3, 3]
  float* center = fops + (size_t)BB * 8 * 9;             // [B, 3]
  double* wpart = (double*)d_ws;                         // 11 f64 per block (1024 blocks)

  hipLaunchKernelGGL(k_part, dim3(BB * 4), dim3(256), 0, stream, X, mask, wpart);
  hipLaunchKernelGGL(k_apply2, dim3(BB * 4), dim3(256), 0, stream,
                     X, mask, wpart, fops, center, h);
}